// Round 1
// baseline (163.779 us; speedup 1.0000x reference)
//
#include <hip/hip_runtime.h>

// CPAMDec: out = scale * (v^T @ softmax(q@k^T)) + x
// Algebraic fusion: energy[n,p,kk] = sum_c x[n,c,p]*wqk[n,kk,c] + bqk[n,kk]
//   with wqk[n] = k_n @ wq  (32x512), bqk[n] = k_n @ bq,  k_n = y_n@wk^T+bk.
// ws layout (floats): wqk [N][K][C] @ 0 ; bqk [N][K] @ N*K*C ; v [N][K][C] after.
// ws requirement: (2*N*K*C + N*K)*4 = ~1.05 MB.

#define N_  8
#define C_  512
#define HW_ 4096
#define K_  32
#define C4_ 128

__global__ __launch_bounds__(256) void prep_kernel(
    const float* __restrict__ y, const float* __restrict__ wq, const float* __restrict__ bq,
    const float* __restrict__ wk, const float* __restrict__ bk,
    const float* __restrict__ wv, const float* __restrict__ bv,
    float* __restrict__ wqk, float* __restrict__ bqk, float* __restrict__ v)
{
    __shared__ float y_row[C_];
    __shared__ float k_row[C4_];
    const int b = blockIdx.x;
    const int n = b >> 5;        // 32 blocks per n
    const int kk = b & 31;
    const int t = threadIdx.x;

    const float* yrow_g = y + ((size_t)n * K_ + kk) * C_;
    y_row[t]       = yrow_g[t];
    y_row[t + 256] = yrow_g[t + 256];
    __syncthreads();

    // v[n,kk,c] = sum_j y[n,kk,j]*wv[c,j] + bv[c]
    for (int c = t; c < C_; c += 256) {
        float s = bv[c];
        const float* wvr = wv + (size_t)c * C_;
        for (int j = 0; j < C_; ++j) s += y_row[j] * wvr[j];
        v[((size_t)n * K_ + kk) * C_ + c] = s;
    }
    // k_row[o] = sum_c y[n,kk,c]*wk[o,c] + bk[o]
    if (t < C4_) {
        float s = bk[t];
        const float* wkr = wk + (size_t)t * C_;
        for (int c = 0; c < C_; ++c) s += y_row[c] * wkr[c];
        k_row[t] = s;
    }
    __syncthreads();

    if (t == 0) {
        float s = 0.f;
        for (int o = 0; o < C4_; ++o) s += k_row[o] * bq[o];
        bqk[n * K_ + kk] = s;
    }
    // wqk[n,kk,c] = sum_o k_row[o]*wq[o,c]   (coalesced over c)
    for (int c = t; c < C_; c += 256) {
        float s = 0.f;
        for (int o = 0; o < C4_; ++o) s += k_row[o] * wq[(size_t)o * C_ + c];
        wqk[((size_t)n * K_ + kk) * C_ + c] = s;
    }
}

__global__ __launch_bounds__(256) void main_kernel(
    const float* __restrict__ x, const float* __restrict__ wqk, const float* __restrict__ bqk,
    const float* __restrict__ v, const float* __restrict__ scale, float* __restrict__ out)
{
    __shared__ float x_lds[32][64];     // c-chunk x p-tile
    __shared__ float wqk_lds[32][33];   // k x c-chunk (+1 pad)
    __shared__ float e_lds[64][33];     // p x k (+1 pad)

    const int b = blockIdx.x;
    const int n = b >> 6;               // 64 pixel-tiles per n
    const int p0 = (b & 63) * 64;
    const int t = threadIdx.x;
    const size_t xbase = (size_t)n * C_ * HW_ + p0;

    // ---- Phase 1: energy[p][k] = sum_c x[c][p]*wqk[k][c] ----
    const int pg = t & 15;              // p = pg*4 + j
    const int kg = t >> 4;              // k = kg*2 + m
    float acc[4][2];
    #pragma unroll
    for (int j = 0; j < 4; ++j) { acc[j][0] = 0.f; acc[j][1] = 0.f; }

    const float* wqk_n = wqk + (size_t)n * K_ * C_;

    for (int cc = 0; cc < C_; cc += 32) {
        __syncthreads();
        // stage x chunk: 32 rows x 64 pixels (512 float4, 2 per thread)
        {
            int fid = t;
            #pragma unroll
            for (int r = 0; r < 2; ++r, fid += 256) {
                const int row = fid >> 4, col4 = (fid & 15) * 4;
                float4 xv = *(const float4*)(x + xbase + (size_t)(cc + row) * HW_ + col4);
                *(float4*)&x_lds[row][col4] = xv;
            }
        }
        // stage wqk chunk: 32 k x 32 c
        {
            const int k = t >> 3, coff = (t & 7) * 4;
            float4 w4 = *(const float4*)(wqk_n + (size_t)k * C_ + cc + coff);
            wqk_lds[k][coff]     = w4.x;
            wqk_lds[k][coff + 1] = w4.y;
            wqk_lds[k][coff + 2] = w4.z;
            wqk_lds[k][coff + 3] = w4.w;
        }
        __syncthreads();

        #pragma unroll
        for (int i = 0; i < 32; ++i) {
            float4 xv = *(const float4*)&x_lds[i][pg * 4];
            float w0 = wqk_lds[kg * 2][i];
            float w1 = wqk_lds[kg * 2 + 1][i];
            acc[0][0] += xv.x * w0;  acc[0][1] += xv.x * w1;
            acc[1][0] += xv.y * w0;  acc[1][1] += xv.y * w1;
            acc[2][0] += xv.z * w0;  acc[2][1] += xv.z * w1;
            acc[3][0] += xv.w * w0;  acc[3][1] += xv.w * w1;
        }
    }
    {
        const float b0 = bqk[n * K_ + kg * 2];
        const float b1 = bqk[n * K_ + kg * 2 + 1];
        #pragma unroll
        for (int j = 0; j < 4; ++j) {
            e_lds[pg * 4 + j][kg * 2]     = acc[j][0] + b0;
            e_lds[pg * 4 + j][kg * 2 + 1] = acc[j][1] + b1;
        }
    }
    __syncthreads();

    // ---- Phase 2: softmax over k (32) per pixel row ----
    if (t < 64) {
        float mx = -1e30f;
        #pragma unroll
        for (int k = 0; k < K_; ++k) mx = fmaxf(mx, e_lds[t][k]);
        float ex[K_];
        float s = 0.f;
        #pragma unroll
        for (int k = 0; k < K_; ++k) { ex[k] = __expf(e_lds[t][k] - mx); s += ex[k]; }
        const float inv = 1.f / s;
        #pragma unroll
        for (int k = 0; k < K_; ++k) e_lds[t][k] = ex[k] * inv;
    }
    __syncthreads();

    // ---- Phase 3: out[c,p] = scale * sum_k v[k][c]*attn[p][k] + x[c,p] ----
    {
        const int ph2 = t & 31;         // pixel pair: p = ph2*2, ph2*2+1
        const int cq = t >> 5;          // c = cq*4 + 32*i
        const int pp = ph2 * 2;

        float attn_r[2][K_];
        #pragma unroll
        for (int k = 0; k < K_; ++k) {
            attn_r[0][k] = e_lds[pp][k];
            attn_r[1][k] = e_lds[pp + 1][k];
        }
        const float* v_n = v + (size_t)n * K_ * C_;
        const float sc = scale[0];

        for (int i = 0; i < 16; ++i) {
            const int c = cq * 4 + 32 * i;
            float a0[4] = {0.f, 0.f, 0.f, 0.f};
            float a1[4] = {0.f, 0.f, 0.f, 0.f};
            #pragma unroll
            for (int k = 0; k < K_; ++k) {
                float4 vv = *(const float4*)(v_n + (size_t)k * C_ + c);
                const float f0 = attn_r[0][k];
                const float f1 = attn_r[1][k];
                a0[0] += vv.x * f0;  a0[1] += vv.y * f0;  a0[2] += vv.z * f0;  a0[3] += vv.w * f0;
                a1[0] += vv.x * f1;  a1[1] += vv.y * f1;  a1[2] += vv.z * f1;  a1[3] += vv.w * f1;
            }
            #pragma unroll
            for (int m = 0; m < 4; ++m) {
                const size_t addr = xbase + (size_t)(c + m) * HW_ + pp;
                float2 xr = *(const float2*)(x + addr);
                float2 ov;
                ov.x = sc * a0[m] + xr.x;
                ov.y = sc * a1[m] + xr.y;
                *(float2*)(out + addr) = ov;
            }
        }
    }
}

extern "C" void kernel_launch(void* const* d_in, const int* in_sizes, int n_in,
                              void* d_out, int out_size, void* d_ws, size_t ws_size,
                              hipStream_t stream) {
    const float* x     = (const float*)d_in[0];
    const float* y     = (const float*)d_in[1];
    const float* wq    = (const float*)d_in[2];
    const float* bq    = (const float*)d_in[3];
    const float* wk    = (const float*)d_in[4];
    const float* bk    = (const float*)d_in[5];
    const float* wv    = (const float*)d_in[6];
    const float* bv    = (const float*)d_in[7];
    const float* scale = (const float*)d_in[8];

    float* ws  = (float*)d_ws;
    float* wqk = ws;                                   // N*K*C
    float* bqk = ws + (size_t)N_ * K_ * C_;            // N*K
    float* v   = bqk + N_ * K_;                        // N*K*C

    prep_kernel<<<N_ * K_, 256, 0, stream>>>(y, wq, bq, wk, bk, wv, bv, wqk, bqk, v);
    main_kernel<<<N_ * 64, 256, 0, stream>>>(x, wqk, bqk, v, scale, (float*)d_out);
}

// Round 2
// 92.707 us; speedup vs baseline: 1.7666x; 1.7666x over previous
//
#include <hip/hip_runtime.h>

// CPAMDec: out = scale * (v^T @ softmax(q@k^T)) + x
// Fused energy: energy[n,p,k] = sum_c x[n,c,p]*wqkT[n,c,k] + bqk[n,k]
//   wqkT[n,c,k] = sum_o krow[n,k,o]*wq[o,c]; bqk[n,k] = sum_o krow[n,k,o]*bq[o]
//   krow = y@wk^T + bk ; v = y@wv^T + bv (stored as 2 j-half partials vp0+vp1)
// ws (floats): wqkT [N][C][K] | bqk [N][K] | vp0 [N][K][C] | vp1 [N][K][C]

#define N_  8
#define C_  512
#define HW_ 4096
#define K_  32

#define WQKT_OFF 0
#define BQK_OFF  (N_ * C_ * K_)
#define VP_OFF   (BQK_OFF + N_ * K_)

__global__ __launch_bounds__(256) void prep_kernel(
    const float* __restrict__ y, const float* __restrict__ wq, const float* __restrict__ bq,
    const float* __restrict__ wk, const float* __restrict__ bk,
    const float* __restrict__ wv, const float* __restrict__ bv,
    float* __restrict__ ws)
{
    float* wqkT = ws + WQKT_OFF;
    float* bqk  = ws + BQK_OFF;
    float* vp   = ws + VP_OFF;
    const int bid = blockIdx.x;
    const int t = threadIdx.x;

    if (bid < 128) {
        // ---- role A: v partials. block = (n, c-tile of 64, j-half of 256) ----
        const int n  = bid >> 4;
        const int ct = (bid >> 1) & 7;
        const int jh = bid & 1;
        const int cl = t & 63;
        const int c  = ct * 64 + cl;
        const int kko = __builtin_amdgcn_readfirstlane(t >> 6);   // 0..3 -> 8 kk each

        const float* yb  = y  + ((size_t)n * K_ + kko * 8) * C_ + jh * 256;  // uniform -> s_load
        const float* wvb = wv + (size_t)c * C_ + jh * 256;                   // per-lane rows
        float acc[8] = {0,0,0,0,0,0,0,0};
        for (int jq = 0; jq < 64; ++jq) {
            float4 w4 = *(const float4*)(wvb + jq * 4);
            #pragma unroll
            for (int u = 0; u < 8; ++u) {
                float4 y4 = *(const float4*)(yb + (size_t)u * C_ + jq * 4);
                acc[u] += y4.x * w4.x + y4.y * w4.y + y4.z * w4.z + y4.w * w4.w;
            }
        }
        const float bvc = (jh == 0) ? bv[c] : 0.0f;
        float* vpo = vp + (size_t)jh * N_ * K_ * C_;
        #pragma unroll
        for (int u = 0; u < 8; ++u)
            vpo[((size_t)n * K_ + kko * 8 + u) * C_ + c] = acc[u] + bvc;
    } else {
        // ---- role B: krow -> bqk, wqkT. block = (n, kk) ----
        __shared__ __align__(16) float kp[2][128];
        __shared__ __align__(16) float kr[128];
        const int b = bid - 128;
        const int n = b >> 5, kk = b & 31;
        const int o = t & 127, half = t >> 7;

        const float* yb  = y  + ((size_t)n * K_ + kk) * C_ + half * 256;  // uniform -> s_load
        const float* wkb = wk + (size_t)o * C_ + half * 256;
        float a = 0.f;
        for (int jq = 0; jq < 64; ++jq) {
            float4 w4 = *(const float4*)(wkb + jq * 4);
            float4 y4 = *(const float4*)(yb + jq * 4);
            a += y4.x * w4.x + y4.y * w4.y + y4.z * w4.z + y4.w * w4.w;
        }
        kp[half][o] = a;
        __syncthreads();
        if (t < 128) kr[t] = kp[0][t] + kp[1][t] + bk[t];
        __syncthreads();
        if (t < 64) {
            float s = kr[t] * bq[t] + kr[t + 64] * bq[t + 64];
            #pragma unroll
            for (int d = 32; d > 0; d >>= 1) s += __shfl_down(s, d);
            if (t == 0) bqk[n * K_ + kk] = s;
        }
        // wqkT[n][c][kk] for c = t, t+256
        const int c1 = t, c2 = t + 256;
        float s1 = 0.f, s2 = 0.f;
        for (int oq = 0; oq < 32; ++oq) {
            float4 k4 = *(const float4*)(&kr[oq * 4]);
            const float* wq0 = wq + (size_t)(oq * 4) * C_;
            s1 += k4.x * wq0[c1] + k4.y * wq0[C_ + c1] + k4.z * wq0[2*C_ + c1] + k4.w * wq0[3*C_ + c1];
            s2 += k4.x * wq0[c2] + k4.y * wq0[C_ + c2] + k4.z * wq0[2*C_ + c2] + k4.w * wq0[3*C_ + c2];
        }
        wqkT[((size_t)n * C_ + c1) * K_ + kk] = s1;
        wqkT[((size_t)n * C_ + c2) * K_ + kk] = s2;
    }
}

__global__ __launch_bounds__(512, 4) void main_kernel(
    const float* __restrict__ x, const float* __restrict__ ws_,
    const float* __restrict__ scale, float* __restrict__ out)
{
    const float* wqkT = ws_ + WQKT_OFF;
    const float* bqk  = ws_ + BQK_OFF;
    const float* vp   = ws_ + VP_OFF;

    __shared__ __align__(16) float e_lds[64][36];       // px x k (pad 36 keeps f4 align)
    __shared__ __align__(16) float v_lds[2][32][64];    // dbuf: k x c-chunk

    const int bid = blockIdx.x;
    const int n  = bid >> 6;
    const int p0 = (bid & 63) * 64;
    const int t  = threadIdx.x;
    const size_t xbase = (size_t)n * C_ * HW_ + p0;

    // ---- Phase 1: energy. thread = (pxl = t&63, kg = t>>6 -> 4 k) ----
    {
        const int pxl = t & 63;
        const int kg  = __builtin_amdgcn_readfirstlane(t >> 6);  // 0..7, wave-uniform
        const float* wr = wqkT + (size_t)n * C_ * K_ + kg * 4;   // [c][k] -> s_load_x4
        const float* xr = x + xbase + pxl;                       // lane->px coalesced
        float a0 = 0.f, a1 = 0.f, a2 = 0.f, a3 = 0.f;
        #pragma unroll 4
        for (int c = 0; c < C_; ++c) {
            float  xv = xr[(size_t)c * HW_];
            float4 w4 = *(const float4*)(wr + (size_t)c * K_);
            a0 += xv * w4.x; a1 += xv * w4.y; a2 += xv * w4.z; a3 += xv * w4.w;
        }
        const float4 b4 = *(const float4*)(bqk + n * K_ + kg * 4);
        e_lds[pxl][kg*4+0] = a0 + b4.x;
        e_lds[pxl][kg*4+1] = a1 + b4.y;
        e_lds[pxl][kg*4+2] = a2 + b4.z;
        e_lds[pxl][kg*4+3] = a3 + b4.w;
    }
    __syncthreads();

    // ---- Phase 2: softmax in PV-thread registers (redundant x16, no barrier) ----
    const int pair = t & 31;      // pixels 2*pair, 2*pair+1
    const int cq   = t >> 5;      // 0..15 -> c = 64*i + cq*4 + m
    float attn[2][K_];
    #pragma unroll
    for (int r = 0; r < 2; ++r) {
        const float* er = e_lds[2 * pair + r];
        float mx = -1e30f;
        #pragma unroll
        for (int k = 0; k < K_; ++k) mx = fmaxf(mx, er[k]);
        float s = 0.f;
        #pragma unroll
        for (int k = 0; k < K_; ++k) { float e = __expf(er[k] - mx); attn[r][k] = e; s += e; }
        const float inv = 1.f / s;
        #pragma unroll
        for (int k = 0; k < K_; ++k) attn[r][k] *= inv;
    }

    // ---- Phase 3: PV + residual. v staged in double-buffered LDS chunks ----
    const int skk = t >> 4, sc4 = (t & 15) * 4;
    const float* vpn0 = vp + ((size_t)n * K_ + skk) * C_ + sc4;
    const float* vpn1 = vpn0 + (size_t)N_ * K_ * C_;
    {
        float4 u0 = *(const float4*)(vpn0);
        float4 u1 = *(const float4*)(vpn1);
        float4 r0; r0.x = u0.x + u1.x; r0.y = u0.y + u1.y; r0.z = u0.z + u1.z; r0.w = u0.w + u1.w;
        *(float4*)&v_lds[0][skk][sc4] = r0;
    }
    const float fs = scale[0];

    for (int i = 0; i < 8; ++i) {
        __syncthreads();
        if (i < 7) {
            float4 u0 = *(const float4*)(vpn0 + (i + 1) * 64);
            float4 u1 = *(const float4*)(vpn1 + (i + 1) * 64);
            float4 r0; r0.x = u0.x + u1.x; r0.y = u0.y + u1.y; r0.z = u0.z + u1.z; r0.w = u0.w + u1.w;
            *(float4*)&v_lds[(i + 1) & 1][skk][sc4] = r0;
        }
        const float* vb = &v_lds[i & 1][0][cq * 4];
        float a00=0.f,a01=0.f,a10=0.f,a11=0.f,a20=0.f,a21=0.f,a30=0.f,a31=0.f;
        #pragma unroll
        for (int k = 0; k < K_; ++k) {
            float4 v4 = *(const float4*)(vb + k * 64);   // half-wave broadcast
            const float f0 = attn[0][k], f1 = attn[1][k];
            a00 += v4.x * f0;  a01 += v4.x * f1;
            a10 += v4.y * f0;  a11 += v4.y * f1;
            a20 += v4.z * f0;  a21 += v4.z * f1;
            a30 += v4.w * f0;  a31 += v4.w * f1;
        }
        const int cb = i * 64 + cq * 4;
        const float av[4][2] = {{a00,a01},{a10,a11},{a20,a21},{a30,a31}};
        #pragma unroll
        for (int m = 0; m < 4; ++m) {
            const size_t addr = xbase + (size_t)(cb + m) * HW_ + 2 * pair;
            float2 xr2 = *(const float2*)(x + addr);
            float2 ov;
            ov.x = fs * av[m][0] + xr2.x;
            ov.y = fs * av[m][1] + xr2.y;
            *(float2*)(out + addr) = ov;
        }
    }
}

extern "C" void kernel_launch(void* const* d_in, const int* in_sizes, int n_in,
                              void* d_out, int out_size, void* d_ws, size_t ws_size,
                              hipStream_t stream) {
    const float* x     = (const float*)d_in[0];
    const float* y     = (const float*)d_in[1];
    const float* wq    = (const float*)d_in[2];
    const float* bq    = (const float*)d_in[3];
    const float* wk    = (const float*)d_in[4];
    const float* bk    = (const float*)d_in[5];
    const float* wv    = (const float*)d_in[6];
    const float* bv    = (const float*)d_in[7];
    const float* scale = (const float*)d_in[8];

    float* ws = (float*)d_ws;

    prep_kernel<<<384, 256, 0, stream>>>(y, wq, bq, wk, bk, wv, bv, ws);
    main_kernel<<<N_ * 64, 512, 0, stream>>>(x, ws, scale, (float*)d_out);
}

// Round 3
// 86.397 us; speedup vs baseline: 1.8956x; 1.0730x over previous
//
#include <hip/hip_runtime.h>

// CPAMDec: out = scale * (v^T @ softmax(q@k^T)) + x
// Fused energy: energy[n,p,k] = sum_c x[n,c,p]*wqkT[n,c,k] + bqk[n,k]
//   wqkT[n,c,k] = sum_o krow[n,k,o]*wq[o,c]; bqk[n,k] = sum_o krow[n,k,o]*bq[o]
//   krow = y@wk^T + bk ; v = y@wv^T + bv (stored as 2 j-half partials vp0+vp1)
// ws (floats): wqkT [N][C][K] | bqk [N][K] | vp0 [N][K][C] | vp1 [N][K][C]

#define N_  8
#define C_  512
#define HW_ 4096
#define K_  32

#define WQKT_OFF 0
#define BQK_OFF  (N_ * C_ * K_)
#define VP_OFF   (BQK_OFF + N_ * K_)

__global__ __launch_bounds__(256) void prep_kernel(
    const float* __restrict__ y, const float* __restrict__ wq, const float* __restrict__ bq,
    const float* __restrict__ wk, const float* __restrict__ bk,
    const float* __restrict__ wv, const float* __restrict__ bv,
    float* __restrict__ ws)
{
    float* wqkT = ws + WQKT_OFF;
    float* bqk  = ws + BQK_OFF;
    float* vp   = ws + VP_OFF;
    const int bid = blockIdx.x;
    const int t = threadIdx.x;

    if (bid < 256) {
        // ---- role A: v partials. block = (n, c-tile of 64, j-half, u-half) ----
        const int n  = bid >> 5;
        const int ct = (bid >> 2) & 7;
        const int jh = (bid >> 1) & 1;
        const int uh = bid & 1;
        const int cl = t & 63;
        const int c  = ct * 64 + cl;
        const int kko = __builtin_amdgcn_readfirstlane(t >> 6);   // 0..3

        const float* yb  = y  + ((size_t)n * K_ + kko * 8 + uh * 4) * C_ + jh * 256; // uniform -> s_load
        const float* wvb = wv + (size_t)c * C_ + jh * 256;                           // per-lane rows
        float acc[4] = {0.f, 0.f, 0.f, 0.f};
        #pragma unroll 4
        for (int jq = 0; jq < 64; ++jq) {
            float4 w4 = *(const float4*)(wvb + jq * 4);
            #pragma unroll
            for (int u = 0; u < 4; ++u) {
                float4 y4 = *(const float4*)(yb + (size_t)u * C_ + jq * 4);
                acc[u] += y4.x * w4.x + y4.y * w4.y + y4.z * w4.z + y4.w * w4.w;
            }
        }
        const float bvc = (jh == 0) ? bv[c] : 0.0f;
        float* vpo = vp + (size_t)jh * N_ * K_ * C_;
        #pragma unroll
        for (int u = 0; u < 4; ++u)
            vpo[((size_t)n * K_ + kko * 8 + uh * 4 + u) * C_ + c] = acc[u] + bvc;
    } else {
        // ---- role B: krow -> bqk, wqkT. block = (n, kk) ----
        __shared__ __align__(16) float kp[2][128];
        __shared__ __align__(16) float kr[128];
        const int b = bid - 256;
        const int n = b >> 5, kk = b & 31;
        const int o = t & 127, half = t >> 7;

        const float* yb  = y  + ((size_t)n * K_ + kk) * C_ + half * 256;  // uniform -> s_load
        const float* wkb = wk + (size_t)o * C_ + half * 256;
        float a = 0.f;
        #pragma unroll 4
        for (int jq = 0; jq < 64; ++jq) {
            float4 w4 = *(const float4*)(wkb + jq * 4);
            float4 y4 = *(const float4*)(yb + jq * 4);
            a += y4.x * w4.x + y4.y * w4.y + y4.z * w4.z + y4.w * w4.w;
        }
        kp[half][o] = a;
        __syncthreads();
        if (t < 128) kr[t] = kp[0][t] + kp[1][t] + bk[t];
        __syncthreads();
        if (t < 64) {
            float s = kr[t] * bq[t] + kr[t + 64] * bq[t + 64];
            #pragma unroll
            for (int d = 32; d > 0; d >>= 1) s += __shfl_down(s, d);
            if (t == 0) bqk[n * K_ + kk] = s;
        }
        // wqkT[n][c][kk] for c = t, t+256
        const int c1 = t, c2 = t + 256;
        float s1 = 0.f, s2 = 0.f;
        for (int oq = 0; oq < 32; ++oq) {
            float4 k4 = *(const float4*)(&kr[oq * 4]);
            const float* wq0 = wq + (size_t)(oq * 4) * C_;
            s1 += k4.x * wq0[c1] + k4.y * wq0[C_ + c1] + k4.z * wq0[2*C_ + c1] + k4.w * wq0[3*C_ + c1];
            s2 += k4.x * wq0[c2] + k4.y * wq0[C_ + c2] + k4.z * wq0[2*C_ + c2] + k4.w * wq0[3*C_ + c2];
        }
        wqkT[((size_t)n * C_ + c1) * K_ + kk] = s1;
        wqkT[((size_t)n * C_ + c2) * K_ + kk] = s2;
    }
}

__global__ __launch_bounds__(512, 4) void main_kernel(
    const float* __restrict__ x, const float* __restrict__ ws_,
    const float* __restrict__ scale, float* __restrict__ out)
{
    const float* wqkT = ws_ + WQKT_OFF;
    const float* bqk  = ws_ + BQK_OFF;
    const float* vp   = ws_ + VP_OFF;

    __shared__ float e_lds[64][37];                     // px x k (37: 2-way max)
    __shared__ __align__(16) float v_lds[2][32][64];    // dbuf: k x c-chunk

    const int bid = blockIdx.x;
    const int n  = bid >> 6;
    const int p0 = (bid & 63) * 64;
    const int t  = threadIdx.x;
    const size_t xbase = (size_t)n * C_ * HW_ + p0;

    // ---- Phase 1: energy. thread = (pxl = t&63, kg = t>>6 -> 4 k) ----
    // Software-pipelined x reads: two 16-deep register batches -> ~32 loads in flight.
    {
        const int pxl = t & 63;
        const int kg  = __builtin_amdgcn_readfirstlane(t >> 6);  // 0..7, wave-uniform
        const float* wr = wqkT + (size_t)n * C_ * K_ + kg * 4;   // [c][k] -> s_load_x4
        const float* xr = x + xbase + pxl;                       // lane->px coalesced
        float a0 = 0.f, a1 = 0.f, a2 = 0.f, a3 = 0.f;

        float xa[16], xb[16];
        #pragma unroll
        for (int j = 0; j < 16; ++j) xa[j] = xr[(size_t)j * HW_];
        #pragma unroll
        for (int j = 0; j < 16; ++j) xb[j] = xr[(size_t)(16 + j) * HW_];

        for (int cc = 0; cc < C_; cc += 32) {
            #pragma unroll
            for (int j = 0; j < 16; ++j) {
                float4 w4 = *(const float4*)(wr + (size_t)(cc + j) * K_);
                a0 += xa[j] * w4.x; a1 += xa[j] * w4.y;
                a2 += xa[j] * w4.z; a3 += xa[j] * w4.w;
            }
            if (cc < 480) {
                #pragma unroll
                for (int j = 0; j < 16; ++j) xa[j] = xr[(size_t)(cc + 32 + j) * HW_];
            }
            #pragma unroll
            for (int j = 0; j < 16; ++j) {
                float4 w4 = *(const float4*)(wr + (size_t)(cc + 16 + j) * K_);
                a0 += xb[j] * w4.x; a1 += xb[j] * w4.y;
                a2 += xb[j] * w4.z; a3 += xb[j] * w4.w;
            }
            if (cc < 480) {
                #pragma unroll
                for (int j = 0; j < 16; ++j) xb[j] = xr[(size_t)(cc + 48 + j) * HW_];
            }
        }
        const float4 b4 = *(const float4*)(bqk + n * K_ + kg * 4);
        e_lds[pxl][kg*4+0] = a0 + b4.x;
        e_lds[pxl][kg*4+1] = a1 + b4.y;
        e_lds[pxl][kg*4+2] = a2 + b4.z;
        e_lds[pxl][kg*4+3] = a3 + b4.w;
    }
    __syncthreads();

    // ---- Phase 2: softmax in PV-thread registers (redundant x16, no barrier) ----
    const int pair = t & 31;      // pixels 2*pair, 2*pair+1
    const int cq   = t >> 5;      // 0..15 -> c = 64*i + cq*4 + m
    float attn[2][K_];
    #pragma unroll
    for (int r = 0; r < 2; ++r) {
        const float* er = e_lds[2 * pair + r];
        float mx = -1e30f;
        #pragma unroll
        for (int k = 0; k < K_; ++k) mx = fmaxf(mx, er[k]);
        float s = 0.f;
        #pragma unroll
        for (int k = 0; k < K_; ++k) { float e = __expf(er[k] - mx); attn[r][k] = e; s += e; }
        const float inv = 1.f / s;
        #pragma unroll
        for (int k = 0; k < K_; ++k) attn[r][k] *= inv;
    }

    // ---- Phase 3: PV + residual. v dbuf in LDS; residual x prefetched 1 chunk ahead ----
    const int skk = t >> 4, sc4 = (t & 15) * 4;
    const float* vpn0 = vp + ((size_t)n * K_ + skk) * C_ + sc4;
    const float* vpn1 = vpn0 + (size_t)N_ * K_ * C_;
    {
        float4 u0 = *(const float4*)(vpn0);
        float4 u1 = *(const float4*)(vpn1);
        float4 r0; r0.x = u0.x + u1.x; r0.y = u0.y + u1.y; r0.z = u0.z + u1.z; r0.w = u0.w + u1.w;
        *(float4*)&v_lds[0][skk][sc4] = r0;
    }
    const float fs = scale[0];

    float2 xres[4];
    #pragma unroll
    for (int m = 0; m < 4; ++m)
        xres[m] = *(const float2*)(x + xbase + (size_t)(cq * 4 + m) * HW_ + 2 * pair);

    for (int i = 0; i < 8; ++i) {
        __syncthreads();
        if (i < 7) {
            float4 u0 = *(const float4*)(vpn0 + (i + 1) * 64);
            float4 u1 = *(const float4*)(vpn1 + (i + 1) * 64);
            float4 r0; r0.x = u0.x + u1.x; r0.y = u0.y + u1.y; r0.z = u0.z + u1.z; r0.w = u0.w + u1.w;
            *(float4*)&v_lds[(i + 1) & 1][skk][sc4] = r0;
        }
        float2 xres_n[4];
        if (i < 7) {
            const int cbn = (i + 1) * 64 + cq * 4;
            #pragma unroll
            for (int m = 0; m < 4; ++m)
                xres_n[m] = *(const float2*)(x + xbase + (size_t)(cbn + m) * HW_ + 2 * pair);
        }
        const float* vb = &v_lds[i & 1][0][cq * 4];
        float a00=0.f,a01=0.f,a10=0.f,a11=0.f,a20=0.f,a21=0.f,a30=0.f,a31=0.f;
        #pragma unroll
        for (int k = 0; k < K_; ++k) {
            float4 v4 = *(const float4*)(vb + k * 64);   // broadcast within half-wave
            const float f0 = attn[0][k], f1 = attn[1][k];
            a00 += v4.x * f0;  a01 += v4.x * f1;
            a10 += v4.y * f0;  a11 += v4.y * f1;
            a20 += v4.z * f0;  a21 += v4.z * f1;
            a30 += v4.w * f0;  a31 += v4.w * f1;
        }
        const int cb = i * 64 + cq * 4;
        const float av[4][2] = {{a00,a01},{a10,a11},{a20,a21},{a30,a31}};
        #pragma unroll
        for (int m = 0; m < 4; ++m) {
            const size_t addr = xbase + (size_t)(cb + m) * HW_ + 2 * pair;
            float2 ov;
            ov.x = fs * av[m][0] + xres[m].x;
            ov.y = fs * av[m][1] + xres[m].y;
            *(float2*)(out + addr) = ov;
        }
        #pragma unroll
        for (int m = 0; m < 4; ++m) xres[m] = xres_n[m];
    }
}

extern "C" void kernel_launch(void* const* d_in, const int* in_sizes, int n_in,
                              void* d_out, int out_size, void* d_ws, size_t ws_size,
                              hipStream_t stream) {
    const float* x     = (const float*)d_in[0];
    const float* y     = (const float*)d_in[1];
    const float* wq    = (const float*)d_in[2];
    const float* bq    = (const float*)d_in[3];
    const float* wk    = (const float*)d_in[4];
    const float* bk    = (const float*)d_in[5];
    const float* wv    = (const float*)d_in[6];
    const float* bv    = (const float*)d_in[7];
    const float* scale = (const float*)d_in[8];

    float* ws = (float*)d_ws;

    prep_kernel<<<512, 256, 0, stream>>>(y, wq, bq, wk, bk, wv, bv, ws);
    main_kernel<<<N_ * 64, 512, 0, stream>>>(x, ws, scale, (float*)d_out);
}